// Round 1
// baseline (453.391 us; speedup 1.0000x reference)
//
#include <hip/hip_runtime.h>

// NodeDropout: out[e] = values[e] if (!flag[src[e]] && !flag[dst[e]]) else 0
// E = 20M edges, N = 1M nodes. Memory-bound streaming + cached gather.
//
// Layouts (per harness contract):
//   d_in[0] = edge_index, int32, [2*E]  (row 0 = src, row 1 = dst)
//   d_in[1] = values,     float32, [E]
//   d_in[2] = nodes_flag, int32 (bool 0/1), [N]
//   d_out   = float32, [E]

__global__ __launch_bounds__(256) void node_dropout_vec4(
    const int4* __restrict__ src4,
    const int4* __restrict__ dst4,
    const float4* __restrict__ val4,
    const int* __restrict__ flag,
    float4* __restrict__ out4,
    int n4)
{
    int i = blockIdx.x * blockDim.x + threadIdx.x;
    if (i >= n4) return;

    int4 s = src4[i];
    int4 d = dst4[i];
    float4 v = val4[i];

    // Gathers: 4 MB table, L2/L3-resident. Predicated select, no divergence.
    float4 o;
    o.x = (flag[s.x] | flag[d.x]) ? 0.0f : v.x;
    o.y = (flag[s.y] | flag[d.y]) ? 0.0f : v.y;
    o.z = (flag[s.z] | flag[d.z]) ? 0.0f : v.z;
    o.w = (flag[s.w] | flag[d.w]) ? 0.0f : v.w;

    out4[i] = o;
}

__global__ __launch_bounds__(256) void node_dropout_tail(
    const int* __restrict__ src,
    const int* __restrict__ dst,
    const float* __restrict__ val,
    const int* __restrict__ flag,
    float* __restrict__ out,
    int begin, int end)
{
    int e = begin + blockIdx.x * blockDim.x + threadIdx.x;
    if (e >= end) return;
    out[e] = (flag[src[e]] | flag[dst[e]]) ? 0.0f : val[e];
}

extern "C" void kernel_launch(void* const* d_in, const int* in_sizes, int n_in,
                              void* d_out, int out_size, void* d_ws, size_t ws_size,
                              hipStream_t stream)
{
    const int* edge_index = (const int*)d_in[0];
    const float* values   = (const float*)d_in[1];
    const int* flag       = (const int*)d_in[2];
    float* out            = (float*)d_out;

    const int E = in_sizes[1];          // number of edges
    const int* src = edge_index;        // row 0
    const int* dst = edge_index + E;    // row 1

    const int n4 = E / 4;
    if (n4 > 0) {
        const int threads = 256;
        const int blocks = (n4 + threads - 1) / threads;
        node_dropout_vec4<<<blocks, threads, 0, stream>>>(
            (const int4*)src, (const int4*)dst, (const float4*)values,
            flag, (float4*)out, n4);
    }
    const int tail_begin = n4 * 4;
    if (tail_begin < E) {
        const int tail_n = E - tail_begin;
        node_dropout_tail<<<(tail_n + 255) / 256, 256, 0, stream>>>(
            src, dst, values, flag, out, tail_begin, E);
    }
}

// Round 3
// 381.377 us; speedup vs baseline: 1.1888x; 1.1888x over previous
//
#include <hip/hip_runtime.h>

// NodeDropout: out[e] = values[e] if (!flag[src[e]] && !flag[dst[e]]) else 0
// E = 20M edges, N = 1M nodes.
//
// R2 = R1 with the compile fix: __builtin_nontemporal_* requires native clang
// vector types, not HIP_vector_type structs. Use ext_vector_type(4).
//
// R1 theory: bit-pack the 4 MB int32 flag table into 125 KB (1M bits) in d_ws
// so it stays L2-resident under 445 MB of streaming traffic (R0 showed 116 MB
// of flag-line refetch = eviction thrash -> gather-latency-bound at 258 us).
// 8 edges/thread => 16 outstanding gathers per lane for MLP; non-temporal
// loads/stores on the use-once streams keep L2 reserved for the flag table.

typedef int   vint4   __attribute__((ext_vector_type(4)));
typedef float vfloat4 __attribute__((ext_vector_type(4)));

__global__ __launch_bounds__(256) void pack_flags(
    const int* __restrict__ flag, unsigned int* __restrict__ packed, int n_words, int n)
{
    int w = blockIdx.x * blockDim.x + threadIdx.x;
    if (w >= n_words) return;
    int base = w * 32;
    unsigned int bits = 0;
    if (base + 32 <= n) {
        const vint4* p = (const vint4*)(flag + base);
        #pragma unroll
        for (int k = 0; k < 8; ++k) {
            vint4 f = p[k];
            bits |= (unsigned int)(f.x != 0) << (k * 4 + 0);
            bits |= (unsigned int)(f.y != 0) << (k * 4 + 1);
            bits |= (unsigned int)(f.z != 0) << (k * 4 + 2);
            bits |= (unsigned int)(f.w != 0) << (k * 4 + 3);
        }
    } else {
        for (int j = 0; j < 32 && base + j < n; ++j)
            bits |= (unsigned int)(flag[base + j] != 0) << j;
    }
    packed[w] = bits;
}

__device__ __forceinline__ float mask_one(
    const unsigned int* __restrict__ packed, int s, int d, float v)
{
    unsigned int ws = packed[s >> 5];
    unsigned int wd = packed[d >> 5];
    unsigned int drop = ((ws >> (s & 31)) | (wd >> (d & 31))) & 1u;
    return drop ? 0.0f : v;
}

__global__ __launch_bounds__(256) void node_dropout_packed(
    const vint4* __restrict__ src4,
    const vint4* __restrict__ dst4,
    const vfloat4* __restrict__ val4,
    const unsigned int* __restrict__ packed,
    vfloat4* __restrict__ out4,
    int n8)   // number of 8-edge groups
{
    int i = blockIdx.x * blockDim.x + threadIdx.x;
    if (i >= n8) return;
    int g = i * 2;   // two vec4 groups per thread

    // Issue all stream loads + all 16 gathers before consuming (MLP).
    vint4 sa = __builtin_nontemporal_load(&src4[g]);
    vint4 sb = __builtin_nontemporal_load(&src4[g + 1]);
    vint4 da = __builtin_nontemporal_load(&dst4[g]);
    vint4 db = __builtin_nontemporal_load(&dst4[g + 1]);
    vfloat4 va = __builtin_nontemporal_load(&val4[g]);
    vfloat4 vb = __builtin_nontemporal_load(&val4[g + 1]);

    vfloat4 oa, ob;
    oa.x = mask_one(packed, sa.x, da.x, va.x);
    oa.y = mask_one(packed, sa.y, da.y, va.y);
    oa.z = mask_one(packed, sa.z, da.z, va.z);
    oa.w = mask_one(packed, sa.w, da.w, va.w);
    ob.x = mask_one(packed, sb.x, db.x, vb.x);
    ob.y = mask_one(packed, sb.y, db.y, vb.y);
    ob.z = mask_one(packed, sb.z, db.z, vb.z);
    ob.w = mask_one(packed, sb.w, db.w, vb.w);

    __builtin_nontemporal_store(oa, &out4[g]);
    __builtin_nontemporal_store(ob, &out4[g + 1]);
}

// Fallback / tail: one edge per thread, unpacked flags.
__global__ __launch_bounds__(256) void node_dropout_tail(
    const int* __restrict__ src,
    const int* __restrict__ dst,
    const float* __restrict__ val,
    const int* __restrict__ flag,
    float* __restrict__ out,
    int begin, int end)
{
    int e = begin + blockIdx.x * blockDim.x + threadIdx.x;
    if (e >= end) return;
    out[e] = (flag[src[e]] | flag[dst[e]]) ? 0.0f : val[e];
}

extern "C" void kernel_launch(void* const* d_in, const int* in_sizes, int n_in,
                              void* d_out, int out_size, void* d_ws, size_t ws_size,
                              hipStream_t stream)
{
    const int* edge_index = (const int*)d_in[0];
    const float* values   = (const float*)d_in[1];
    const int* flag       = (const int*)d_in[2];
    float* out            = (float*)d_out;

    const int E = in_sizes[1];          // number of edges
    const int N = in_sizes[2];          // number of nodes
    const int* src = edge_index;        // row 0
    const int* dst = edge_index + E;    // row 1

    const int n_words = (N + 31) / 32;
    const size_t need = (size_t)n_words * sizeof(unsigned int);

    if (ws_size >= need) {
        unsigned int* packed = (unsigned int*)d_ws;
        pack_flags<<<(n_words + 255) / 256, 256, 0, stream>>>(flag, packed, n_words, N);

        const int n8 = E / 8;
        if (n8 > 0) {
            node_dropout_packed<<<(n8 + 255) / 256, 256, 0, stream>>>(
                (const vint4*)src, (const vint4*)dst, (const vfloat4*)values,
                packed, (vfloat4*)out, n8);
        }
        const int tail_begin = n8 * 8;
        if (tail_begin < E) {
            node_dropout_tail<<<(E - tail_begin + 255) / 256, 256, 0, stream>>>(
                src, dst, values, flag, out, tail_begin, E);
        }
    } else {
        // Workspace too small: direct path (R0 behavior).
        node_dropout_tail<<<(E + 255) / 256, 256, 0, stream>>>(
            src, dst, values, flag, out, 0, E);
    }
}

// Round 4
// 362.512 us; speedup vs baseline: 1.2507x; 1.0520x over previous
//
#include <hip/hip_runtime.h>

// NodeDropout: out[e] = values[e] if (!flag[src[e]] && !flag[dst[e]]) else 0
// E = 20M edges, N = 1M nodes.
//
// R3: the 125 KB bit-packed flag table moves into LDS (gfx950 has 160 KiB/CU).
// R2 evidence: FETCH dropped to 121 MB (L2-thrash fixed) but kernel stuck at
// 157 us, 1.3 TB/s, VALUBusy 3.9% -> gather pipe (TCP scatter issue + L1-miss
// line fills into L2, ~3.8 GB of line traffic) is the limiter, not streams.
// ds_read_b32 serves 64 scattered lanes at bank granularity (~10 cyc w/ random
// ~4-way conflicts) -> gathers become ~10 us total; streams (400 MB) become
// the roofline (~65 us). One 1024-thread block per CU, 125 KB dynamic LDS
// (hipFuncSetAttribute; falls back to the R2 global-packed kernel on failure).

typedef int   vint4   __attribute__((ext_vector_type(4)));
typedef float vfloat4 __attribute__((ext_vector_type(4)));

__global__ __launch_bounds__(256) void pack_flags(
    const int* __restrict__ flag, unsigned int* __restrict__ packed, int n_words, int n)
{
    int w = blockIdx.x * blockDim.x + threadIdx.x;
    if (w >= n_words) return;
    int base = w * 32;
    unsigned int bits = 0;
    if (base + 32 <= n) {
        const vint4* p = (const vint4*)(flag + base);
        #pragma unroll
        for (int k = 0; k < 8; ++k) {
            vint4 f = p[k];
            bits |= (unsigned int)(f.x != 0) << (k * 4 + 0);
            bits |= (unsigned int)(f.y != 0) << (k * 4 + 1);
            bits |= (unsigned int)(f.z != 0) << (k * 4 + 2);
            bits |= (unsigned int)(f.w != 0) << (k * 4 + 3);
        }
    } else {
        for (int j = 0; j < 32 && base + j < n; ++j)
            bits |= (unsigned int)(flag[base + j] != 0) << j;
    }
    packed[w] = bits;
}

// ---------------- LDS-table main kernel ----------------

__device__ __forceinline__ float mask_lds(
    const unsigned int* tab, int s, int d, float v)
{
    unsigned int ws = tab[s >> 5];
    unsigned int wd = tab[d >> 5];
    unsigned int drop = ((ws >> (s & 31)) | (wd >> (d & 31))) & 1u;
    return drop ? 0.0f : v;
}

__global__ __launch_bounds__(1024, 4) void node_dropout_lds(
    const vint4* __restrict__ src4,
    const vint4* __restrict__ dst4,
    const vfloat4* __restrict__ val4,
    const unsigned int* __restrict__ packed,
    vfloat4* __restrict__ out4,
    int n_words,
    int n16)   // number of 16-edge groups
{
    extern __shared__ unsigned int tab[];
    for (int w = threadIdx.x; w < n_words; w += blockDim.x)
        tab[w] = packed[w];
    __syncthreads();

    const int stride = gridDim.x * blockDim.x;
    for (int i = blockIdx.x * blockDim.x + threadIdx.x; i < n16; i += stride) {
        int g = i * 4;  // 4 consecutive vec4 groups = 16 edges

        vint4 s0 = __builtin_nontemporal_load(&src4[g + 0]);
        vint4 s1 = __builtin_nontemporal_load(&src4[g + 1]);
        vint4 s2 = __builtin_nontemporal_load(&src4[g + 2]);
        vint4 s3 = __builtin_nontemporal_load(&src4[g + 3]);
        vint4 d0 = __builtin_nontemporal_load(&dst4[g + 0]);
        vint4 d1 = __builtin_nontemporal_load(&dst4[g + 1]);
        vint4 d2 = __builtin_nontemporal_load(&dst4[g + 2]);
        vint4 d3 = __builtin_nontemporal_load(&dst4[g + 3]);
        vfloat4 v0 = __builtin_nontemporal_load(&val4[g + 0]);
        vfloat4 v1 = __builtin_nontemporal_load(&val4[g + 1]);
        vfloat4 v2 = __builtin_nontemporal_load(&val4[g + 2]);
        vfloat4 v3 = __builtin_nontemporal_load(&val4[g + 3]);

        vfloat4 o0, o1, o2, o3;
        o0.x = mask_lds(tab, s0.x, d0.x, v0.x);
        o0.y = mask_lds(tab, s0.y, d0.y, v0.y);
        o0.z = mask_lds(tab, s0.z, d0.z, v0.z);
        o0.w = mask_lds(tab, s0.w, d0.w, v0.w);
        o1.x = mask_lds(tab, s1.x, d1.x, v1.x);
        o1.y = mask_lds(tab, s1.y, d1.y, v1.y);
        o1.z = mask_lds(tab, s1.z, d1.z, v1.z);
        o1.w = mask_lds(tab, s1.w, d1.w, v1.w);
        o2.x = mask_lds(tab, s2.x, d2.x, v2.x);
        o2.y = mask_lds(tab, s2.y, d2.y, v2.y);
        o2.z = mask_lds(tab, s2.z, d2.z, v2.z);
        o2.w = mask_lds(tab, s2.w, d2.w, v2.w);
        o3.x = mask_lds(tab, s3.x, d3.x, v3.x);
        o3.y = mask_lds(tab, s3.y, d3.y, v3.y);
        o3.z = mask_lds(tab, s3.z, d3.z, v3.z);
        o3.w = mask_lds(tab, s3.w, d3.w, v3.w);

        __builtin_nontemporal_store(o0, &out4[g + 0]);
        __builtin_nontemporal_store(o1, &out4[g + 1]);
        __builtin_nontemporal_store(o2, &out4[g + 2]);
        __builtin_nontemporal_store(o3, &out4[g + 3]);
    }
}

// ---------------- R2 fallback kernel (global packed table) ----------------

__device__ __forceinline__ float mask_one(
    const unsigned int* __restrict__ packed, int s, int d, float v)
{
    unsigned int ws = packed[s >> 5];
    unsigned int wd = packed[d >> 5];
    unsigned int drop = ((ws >> (s & 31)) | (wd >> (d & 31))) & 1u;
    return drop ? 0.0f : v;
}

__global__ __launch_bounds__(256) void node_dropout_packed(
    const vint4* __restrict__ src4,
    const vint4* __restrict__ dst4,
    const vfloat4* __restrict__ val4,
    const unsigned int* __restrict__ packed,
    vfloat4* __restrict__ out4,
    int n8)
{
    int i = blockIdx.x * blockDim.x + threadIdx.x;
    if (i >= n8) return;
    int g = i * 2;

    vint4 sa = __builtin_nontemporal_load(&src4[g]);
    vint4 sb = __builtin_nontemporal_load(&src4[g + 1]);
    vint4 da = __builtin_nontemporal_load(&dst4[g]);
    vint4 db = __builtin_nontemporal_load(&dst4[g + 1]);
    vfloat4 va = __builtin_nontemporal_load(&val4[g]);
    vfloat4 vb = __builtin_nontemporal_load(&val4[g + 1]);

    vfloat4 oa, ob;
    oa.x = mask_one(packed, sa.x, da.x, va.x);
    oa.y = mask_one(packed, sa.y, da.y, va.y);
    oa.z = mask_one(packed, sa.z, da.z, va.z);
    oa.w = mask_one(packed, sa.w, da.w, va.w);
    ob.x = mask_one(packed, sb.x, db.x, vb.x);
    ob.y = mask_one(packed, sb.y, db.y, vb.y);
    ob.z = mask_one(packed, sb.z, db.z, vb.z);
    ob.w = mask_one(packed, sb.w, db.w, vb.w);

    __builtin_nontemporal_store(oa, &out4[g]);
    __builtin_nontemporal_store(ob, &out4[g + 1]);
}

// Tail: one edge per thread, unpacked flags.
__global__ __launch_bounds__(256) void node_dropout_tail(
    const int* __restrict__ src,
    const int* __restrict__ dst,
    const float* __restrict__ val,
    const int* __restrict__ flag,
    float* __restrict__ out,
    int begin, int end)
{
    int e = begin + blockIdx.x * blockDim.x + threadIdx.x;
    if (e >= end) return;
    out[e] = (flag[src[e]] | flag[dst[e]]) ? 0.0f : val[e];
}

extern "C" void kernel_launch(void* const* d_in, const int* in_sizes, int n_in,
                              void* d_out, int out_size, void* d_ws, size_t ws_size,
                              hipStream_t stream)
{
    const int* edge_index = (const int*)d_in[0];
    const float* values   = (const float*)d_in[1];
    const int* flag       = (const int*)d_in[2];
    float* out            = (float*)d_out;

    const int E = in_sizes[1];
    const int N = in_sizes[2];
    const int* src = edge_index;
    const int* dst = edge_index + E;

    const int n_words = (N + 31) / 32;
    const size_t need = (size_t)n_words * sizeof(unsigned int);
    const size_t lds_bytes = (size_t)n_words * sizeof(unsigned int);

    if (ws_size >= need) {
        unsigned int* packed = (unsigned int*)d_ws;
        pack_flags<<<(n_words + 255) / 256, 256, 0, stream>>>(flag, packed, n_words, N);

        bool lds_ok = (lds_bytes <= 160 * 1024);
        if (lds_ok && lds_bytes > 64 * 1024) {
            lds_ok = (hipFuncSetAttribute(
                          (const void*)node_dropout_lds,
                          hipFuncAttributeMaxDynamicSharedMemorySize,
                          (int)lds_bytes) == hipSuccess);
        }

        if (lds_ok) {
            const int n16 = E / 16;
            if (n16 > 0) {
                node_dropout_lds<<<256, 1024, lds_bytes, stream>>>(
                    (const vint4*)src, (const vint4*)dst, (const vfloat4*)values,
                    packed, (vfloat4*)out, n_words, n16);
            }
            const int tail_begin = n16 * 16;
            if (tail_begin < E) {
                node_dropout_tail<<<(E - tail_begin + 255) / 256, 256, 0, stream>>>(
                    src, dst, values, flag, out, tail_begin, E);
            }
        } else {
            const int n8 = E / 8;
            if (n8 > 0) {
                node_dropout_packed<<<(n8 + 255) / 256, 256, 0, stream>>>(
                    (const vint4*)src, (const vint4*)dst, (const vfloat4*)values,
                    packed, (vfloat4*)out, n8);
            }
            const int tail_begin = n8 * 8;
            if (tail_begin < E) {
                node_dropout_tail<<<(E - tail_begin + 255) / 256, 256, 0, stream>>>(
                    src, dst, values, flag, out, tail_begin, E);
            }
        }
    } else {
        node_dropout_tail<<<(E + 255) / 256, 256, 0, stream>>>(
            src, dst, values, flag, out, 0, E);
    }
}